// Round 2
// baseline (63.114 us; speedup 1.0000x reference)
//
#include <hip/hip_runtime.h>
#include <math.h>

#define NT 256
#define NACC 16

constexpr unsigned SVOX = 96u * 160u * 160u;   // 2,457,600 voxels per batch item
constexpr unsigned VTOT = 2u * SVOX;           // 4,915,200 total voxels
constexpr double SMOOTH = 1e-5;
#define L2E 1.44269504088896340736f
#define LN2 0.69314718055994530942f

// Accumulator layout (16):
// 0..3  intersect[c]; 4..7 sumprob[c]; 8..11 count[c]
// 12 bce-sum (pos), 13 bce-sum (neg), 14 pos count, 15 neg count

__device__ __forceinline__ float fexp2(float x) { return __builtin_amdgcn_exp2f(x); }
__device__ __forceinline__ float flog2(float x) { return __builtin_amdgcn_logf(x); }
__device__ __forceinline__ float frcp(float x)  { return __builtin_amdgcn_rcpf(x); }

__global__ __launch_bounds__(NT)
void jedl_stage1(const float* __restrict__ seg, const float* __restrict__ edge,
                 const int* __restrict__ smask, const int* __restrict__ emask,
                 float* __restrict__ part) {
    float acc[NACC];
#pragma unroll
    for (int i = 0; i < NACC; ++i) acc[i] = 0.f;

    const unsigned ngroups = VTOT / 4u;
    const unsigned stride = gridDim.x * NT;
    for (unsigned g = blockIdx.x * NT + threadIdx.x; g < ngroups; g += stride) {
        const unsigned v = g * 4u;                       // voxel quad base
        // batch select without division: seg offset = v + 3*SVOX if second batch
        const unsigned segoff = v + ((v >= SVOX) ? 3u * SVOX : 0u);
        const float* segb = seg + segoff;
        const float4 x0 = *(const float4*)(segb);
        const float4 x1 = *(const float4*)(segb + SVOX);
        const float4 x2 = *(const float4*)(segb + 2u * SVOX);
        const float4 x3 = *(const float4*)(segb + 3u * SVOX);
        const int4   tm = *(const int4*)(smask + v);
        const float4 ex = *(const float4*)(edge + v);
        const int4   em = *(const int4*)(emask + v);

#define PROC(j) do {                                                          \
        const float e0 = fexp2(x0.j * L2E), e1 = fexp2(x1.j * L2E);           \
        const float e2 = fexp2(x2.j * L2E), e3 = fexp2(x3.j * L2E);           \
        const float inv = frcp(e0 + e1 + e2 + e3);                            \
        const float p0 = e0 * inv, p1 = e1 * inv, p2 = e2 * inv, p3 = e3 * inv;\
        acc[4] += p0; acc[5] += p1; acc[6] += p2; acc[7] += p3;               \
        const int t = tm.j;                                                   \
        acc[0] += (t == 0) ? p0 : 0.f;                                        \
        acc[1] += (t == 1) ? p1 : 0.f;                                        \
        acc[2] += (t == 2) ? p2 : 0.f;                                        \
        acc[3] += (t == 3) ? p3 : 0.f;                                        \
        acc[8]  += (float)(t == 0); acc[9]  += (float)(t == 1);               \
        acc[10] += (float)(t == 2); acc[11] += (float)(t == 3);               \
        const float xx = ex.j; const int tt = em.j;                           \
        const float sp = LN2 * flog2(1.f + fexp2(-fabsf(xx) * L2E));          \
        const float bce = fmaxf(xx, 0.f) - xx * (float)tt + sp;               \
        acc[12] += (tt == 1) ? bce : 0.f;                                     \
        acc[13] += (tt == 0) ? bce : 0.f;                                     \
        acc[14] += (float)(tt == 1); acc[15] += (float)(tt == 0);             \
    } while (0)

        PROC(x); PROC(y); PROC(z); PROC(w);
#undef PROC
    }

    // wave (64-lane) shuffle reduction
#pragma unroll
    for (int i = 0; i < NACC; ++i) {
        float v = acc[i];
        for (int off = 32; off > 0; off >>= 1) v += __shfl_down(v, off);
        acc[i] = v;
    }

    __shared__ float wpart[NT / 64][NACC];
    const int lane = threadIdx.x & 63, wid = threadIdx.x >> 6;
    if (lane == 0) {
#pragma unroll
        for (int i = 0; i < NACC; ++i) wpart[wid][i] = acc[i];
    }
    __syncthreads();
    if (threadIdx.x == 0) {
#pragma unroll
        for (int i = 0; i < NACC; ++i) {
            float s = 0.f;
            for (int w = 0; w < NT / 64; ++w) s += wpart[w][i];
            part[blockIdx.x * NACC + i] = s;
        }
    }
}

__global__ __launch_bounds__(NT)
void jedl_stage2(const float* __restrict__ part, int nblocks, float* __restrict__ out) {
    __shared__ double red[NT];
    __shared__ double tot[NACC];
    const int tid = threadIdx.x;
    const int a = tid & (NACC - 1);
    double ssum = 0.0;
    for (int r = tid >> 4; r < nblocks; r += NT / NACC)
        ssum += (double)part[r * NACC + a];
    red[tid] = ssum;
    __syncthreads();
    if (tid < NACC) {
        double t = 0.0;
        for (int k = 0; k < NT / NACC; ++k) t += red[tid + NACC * k];
        tot[tid] = t;
    }
    __syncthreads();
    if (tid == 0) {
        double dsum = 0.0;
        for (int c = 0; c < 4; ++c)
            dsum += (2.0 * tot[c] + SMOOTH) / (tot[4 + c] + tot[8 + c] + SMOOTH);
        const double region = 1.0 - dsum / 4.0;
        const double bp = tot[12], bn = tot[13], pc = tot[14], nc = tot[15];
        const double sum = pc + nc;
        const double eloss = (nc * bp + pc * bn) / (sum * (double)VTOT);
        out[0] = (float)region;
        out[1] = (float)eloss;
    }
}

extern "C" void kernel_launch(void* const* d_in, const int* in_sizes, int n_in,
                              void* d_out, int out_size, void* d_ws, size_t ws_size,
                              hipStream_t stream) {
    const float* seg   = (const float*)d_in[0];
    const float* edge  = (const float*)d_in[1];
    const int*   smask = (const int*)d_in[2];
    const int*   emask = (const int*)d_in[3];
    float* out  = (float*)d_out;
    float* part = (float*)d_ws;

    int nb = 2048;
    const size_t need = (size_t)nb * NACC * sizeof(float);
    if (ws_size < need) nb = (int)(ws_size / (NACC * sizeof(float)));
    if (nb < 1) nb = 1;

    jedl_stage1<<<nb, NT, 0, stream>>>(seg, edge, smask, emask, part);
    jedl_stage2<<<1, NT, 0, stream>>>(part, nb, out);
}

// Round 3
// 30.948 us; speedup vs baseline: 2.0394x; 2.0394x over previous
//
#include <hip/hip_runtime.h>
#include <math.h>

#define NT 256
#define NT2 1024
#define NB 2048

constexpr unsigned SVOX = 96u * 160u * 160u;   // 2,457,600 voxels per batch item
constexpr unsigned VTOT = 2u * SVOX;           // 4,915,200 voxels total
constexpr unsigned NQUAD = VTOT / 4u;          // 1,228,800 quads
constexpr unsigned CHUNK = NQUAD / NB;         // 600 quads per block (exact)
constexpr unsigned TAIL = CHUNK - 2u * NT;     // 88
constexpr double SMOOTH = 1e-5;
#define L2E 1.44269504088896340736f
#define LN2 0.69314718055994530942f

__device__ __forceinline__ float fexp2(float x) { return __builtin_amdgcn_exp2f(x); }
__device__ __forceinline__ float flog2(float x) { return __builtin_amdgcn_logf(x); }
__device__ __forceinline__ float frcp(float x)  { return __builtin_amdgcn_rcpf(x); }

struct Quad {
    float4 x0, x1, x2, x3;   // 4 softmax channels
    int4   tm;               // seg mask
    float4 ex;               // edge logits
    int4   em;               // edge mask
};

__device__ __forceinline__ Quad loadq(const float* __restrict__ seg,
                                      const float* __restrict__ edge,
                                      const int* __restrict__ sm,
                                      const int* __restrict__ em,
                                      unsigned v, unsigned segadd) {
    Quad q;
    const float* sb = seg + v + segadd;
    q.x0 = *(const float4*)(sb);
    q.x1 = *(const float4*)(sb + SVOX);
    q.x2 = *(const float4*)(sb + 2u * SVOX);
    q.x3 = *(const float4*)(sb + 3u * SVOX);
    q.tm = *(const int4*)(sm + v);
    q.ex = *(const float4*)(edge + v);
    q.em = *(const int4*)(em + v);
    return q;
}

// facc: 0..3 intersect[c], 4..7 sumprob[c], 8 bcePos, 9 bceNeg
// ccnt: packed 4x16-bit class counts; pncnt: pos<<16 | neg
__device__ __forceinline__ void procq(const Quad& q, float* facc,
                                      unsigned long long& ccnt, unsigned& pncnt) {
#define PROC(j) do {                                                           \
        const float e0 = fexp2(q.x0.j * L2E), e1 = fexp2(q.x1.j * L2E);        \
        const float e2 = fexp2(q.x2.j * L2E), e3 = fexp2(q.x3.j * L2E);        \
        const float inv = frcp(e0 + e1 + e2 + e3);                             \
        const float p0 = e0 * inv, p1 = e1 * inv, p2 = e2 * inv, p3 = e3 * inv;\
        facc[4] += p0; facc[5] += p1; facc[6] += p2; facc[7] += p3;            \
        const int t = q.tm.j;                                                  \
        facc[0] += (t == 0) ? p0 : 0.f;                                        \
        facc[1] += (t == 1) ? p1 : 0.f;                                        \
        facc[2] += (t == 2) ? p2 : 0.f;                                        \
        facc[3] += (t == 3) ? p3 : 0.f;                                        \
        ccnt += 1ull << (16 * t);                                              \
        const float xx = q.ex.j; const int tt = q.em.j;                        \
        const float sp = LN2 * flog2(1.f + fexp2(-fabsf(xx) * L2E));           \
        const float bce = fmaxf(xx, 0.f) - xx * (float)tt + sp;                \
        facc[8] += (tt == 1) ? bce : 0.f;                                      \
        facc[9] += (tt == 0) ? bce : 0.f;                                      \
        pncnt += (tt == 1) ? 0x10000u : 1u;                                    \
    } while (0)
    PROC(x); PROC(y); PROC(z); PROC(w);
#undef PROC
}

__global__ __launch_bounds__(NT)
void jedl_stage1(const float* __restrict__ seg, const float* __restrict__ edge,
                 const int* __restrict__ smask, const int* __restrict__ emask,
                 float* __restrict__ part) {
    const unsigned tid = threadIdx.x;
    const unsigned bid = blockIdx.x;
    const unsigned qbase = bid * CHUNK;
    // block-uniform batch select (chunks never straddle: 614,400 % 600 == 0)
    const unsigned segadd = (bid >= NB / 2) ? 3u * SVOX : 0u;

    float facc[10];
#pragma unroll
    for (int i = 0; i < 10; ++i) facc[i] = 0.f;
    unsigned long long ccnt = 0ull;
    unsigned pncnt = 0u;

    const bool tail = tid < TAIL;
    // 2-deep pipeline: load A, load B, proc A, load C(masked), proc B, proc C
    Quad qa = loadq(seg, edge, smask, emask, (qbase + tid) * 4u, segadd);
    Quad qb = loadq(seg, edge, smask, emask, (qbase + tid + NT) * 4u, segadd);
    procq(qa, facc, ccnt, pncnt);
    Quad qc;
    if (tail) qc = loadq(seg, edge, smask, emask, (qbase + tid + 2u * NT) * 4u, segadd);
    procq(qb, facc, ccnt, pncnt);
    if (tail) procq(qc, facc, ccnt, pncnt);

    // wave (64-lane) shuffle reduction
#pragma unroll
    for (int i = 0; i < 10; ++i) {
        float v = facc[i];
        for (int off = 32; off > 0; off >>= 1) v += __shfl_down(v, off);
        facc[i] = v;
    }
    for (int off = 32; off > 0; off >>= 1) ccnt += __shfl_down(ccnt, off);
    for (int off = 32; off > 0; off >>= 1) pncnt += __shfl_down(pncnt, off);

    __shared__ float wl[NT / 64][10];
    __shared__ unsigned long long wc[NT / 64];
    __shared__ unsigned wp[NT / 64];
    const int lane = threadIdx.x & 63, wid = threadIdx.x >> 6;
    if (lane == 0) {
#pragma unroll
        for (int i = 0; i < 10; ++i) wl[wid][i] = facc[i];
        wc[wid] = ccnt;
        wp[wid] = pncnt;
    }
    __syncthreads();
    if (tid == 0) {
        float s[10];
#pragma unroll
        for (int i = 0; i < 10; ++i)
            s[i] = wl[0][i] + wl[1][i] + wl[2][i] + wl[3][i];
        const unsigned long long c = wc[0] + wc[1] + wc[2] + wc[3];   // fields <= 3072, no carry
        const unsigned pn = wp[0] + wp[1] + wp[2] + wp[3];
        // transposed layout for coalesced stage-2 reads: part[acc*NB + bid]
#pragma unroll
        for (int i = 0; i < 8; ++i) part[i * NB + bid] = s[i];
#pragma unroll
        for (int cix = 0; cix < 4; ++cix)
            part[(8 + cix) * NB + bid] = (float)((c >> (16 * cix)) & 0xffffull);
        part[12 * NB + bid] = s[8];                       // bce pos sum
        part[13 * NB + bid] = s[9];                       // bce neg sum
        part[14 * NB + bid] = (float)(pn >> 16);          // pos count
        part[15 * NB + bid] = (float)(pn & 0xffffu);      // neg count
    }
}

__global__ __launch_bounds__(NT2)
void jedl_stage2(const float* __restrict__ part, float* __restrict__ out) {
    __shared__ double tot[16];
    const int tid = threadIdx.x;
    const int w = tid >> 6, lane = tid & 63;      // 16 waves, one accumulator each
    const float4* p4 = (const float4*)(part + w * NB);
    double d = 0.0;
#pragma unroll
    for (int it = 0; it < NB / (64 * 4); ++it) {
        const float4 v = p4[it * 64 + lane];
        d += (double)v.x + (double)v.y + (double)v.z + (double)v.w;
    }
    for (int off = 32; off > 0; off >>= 1) d += __shfl_down(d, off);
    if (lane == 0) tot[w] = d;
    __syncthreads();
    if (tid == 0) {
        double dsum = 0.0;
        for (int c = 0; c < 4; ++c)
            dsum += (2.0 * tot[c] + SMOOTH) / (tot[4 + c] + tot[8 + c] + SMOOTH);
        const double region = 1.0 - dsum / 4.0;
        const double bp = tot[12], bn = tot[13], pc = tot[14], nc = tot[15];
        const double sum = pc + nc;
        const double eloss = (nc * bp + pc * bn) / (sum * (double)VTOT);
        out[0] = (float)region;
        out[1] = (float)eloss;
    }
}

extern "C" void kernel_launch(void* const* d_in, const int* in_sizes, int n_in,
                              void* d_out, int out_size, void* d_ws, size_t ws_size,
                              hipStream_t stream) {
    const float* seg   = (const float*)d_in[0];
    const float* edge  = (const float*)d_in[1];
    const int*   smask = (const int*)d_in[2];
    const int*   emask = (const int*)d_in[3];
    float* out  = (float*)d_out;
    float* part = (float*)d_ws;   // 16 * NB floats = 128 KB

    jedl_stage1<<<NB, NT, 0, stream>>>(seg, edge, smask, emask, part);
    jedl_stage2<<<1, NT2, 0, stream>>>(part, out);
}